// Round 2
// baseline (200.636 us; speedup 1.0000x reference)
//
#include <hip/hip_runtime.h>

// Segmented CRF forward (OneCrfCCKSDecoder), exp-domain + MFMA, R10.1
// (identical to R10 — previous bench was an infra failure, resubmitting).
// T=128, B=512, E=128, EVENTLEN=8, NEG=-10000.
//
// R9 post-mortem: 8 waves j-split coupled through LDS H + s_barrier every
// step; per-step cost ~1.6K cycles dominated by inter-wave sync skew (R8->R9
// gave only 1.29x for 8x the MFMA parallelism => fixed sync term dominates).
//
// R10: wave-private recurrence. One wave owns 16 batches and all 128 j:
// 8 j-tiles x 4 K-slices = 32 MFMAs/step, full exp(T) in registers
// (128 VGPRs). The D->B transpose of h goes through a per-wave 4KB LDS
// buffer; same wave produces and consumes => DS pipe in-order, NO s_barrier,
// only __builtin_amdgcn_wave_barrier() (compile-time fence, 0 instructions).
// Boundary steps (alpha + exact cmax renorm) are pure shfl_xor reductions.
// Grid = 32 blocks x 64 threads: 32 independent waves, zero inter-wave sync.
//
// Layouts identical to validated R9 (absmax 0.0), w -> jt:
//   A[m=lane&15][k=32kap+8q+i], B[k=32kap+8q+i][n=lane&15],
//   D[m=4q+r][n=lane&15]; j = 16jt + (m-role), n = batch.
// Renorm: fixed e^-6 per-step scale in efi (M += 6), exact per-batch
// max-renorm folded into efi at every event boundary. MFMA accumulation
// keeps R9's exact da/db chain order.

typedef _Float16 f16x4 __attribute__((ext_vector_type(4)));
typedef _Float16 f16x8 __attribute__((ext_vector_type(8)));
typedef float    f32x4 __attribute__((ext_vector_type(4)));

#define NEG_VAL   (-10000.0f)
#define C_SCALE   0.0024787521766663585f   // e^-6
#define LOG_C     6.0f

__global__ __launch_bounds__(64, 1)
void crf_fwd(const float* __restrict__ feats,   // [128][512][128] f32
             const float* __restrict__ trans,   // [128][128] f32
             float* __restrict__ out)
{
    const int lane = threadIdx.x & 63;
    const int bloc = lane & 15;        // batch-in-tile (n role; m role for A)
    const int q    = lane >> 4;        // quad 0..3
    const int b    = blockIdx.x * 16 + bloc;   // global batch

    // ---- A fragments: exp(T) rows j = 16jt + bloc, k = 32kap + 8q + i ----
    f16x8 Afrag[8][4];
    #pragma unroll
    for (int jt = 0; jt < 8; ++jt) {
        const float* rowp = trans + (size_t)(16 * jt + bloc) * 128;
        #pragma unroll
        for (int kap = 0; kap < 4; ++kap) {
            const f32x4* p = (const f32x4*)(rowp + 32 * kap + 8 * q);
            f32x4 x = p[0], y = p[1];
            f16x8 f;
            f[0] = (_Float16)__expf(x[0]); f[1] = (_Float16)__expf(x[1]);
            f[2] = (_Float16)__expf(x[2]); f[3] = (_Float16)__expf(x[3]);
            f[4] = (_Float16)__expf(y[0]); f[5] = (_Float16)__expf(y[1]);
            f[6] = (_Float16)__expf(y[2]); f[7] = (_Float16)__expf(y[3]);
            Afrag[jt][kap] = f;
        }
    }
    // te in D layout: te[jt][r] = exp(trans[127][16jt + 4q + r])
    f32x4 te[8];
    #pragma unroll
    for (int jt = 0; jt < 8; ++jt) {
        f32x4 x = *(const f32x4*)(trans + 127 * 128 + 16 * jt + 4 * q);
        te[jt][0] = __expf(x[0]); te[jt][1] = __expf(x[1]);
        te[jt][2] = __expf(x[2]); te[jt][3] = __expf(x[3]);
    }

    // ---- per-wave LDS: H (16 batches x 128 k f16, XOR-swizzled 16B chunks)
    __shared__ __align__(16) char Hbuf[4096];

    int waddr[8], raddr[4];
    #pragma unroll
    for (int jt = 0; jt < 8; ++jt)
        waddr[jt] = bloc * 256 + (((2 * jt + (q >> 1)) ^ bloc) * 16) + 8 * (q & 1);
    #pragma unroll
    for (int kap = 0; kap < 4; ++kap)
        raddr[kap] = bloc * 256 + (((4 * kap + q) ^ bloc) * 16);

    // ---- feat pipeline: lane needs feat[t][b][16jt + 4q + r], jt=0..7 ----
    const float* fb = feats + (size_t)b * 128 + 4 * q;
    f32x4 efi[8], r1v[8], r2v[8];
    #pragma unroll
    for (int jt = 0; jt < 8; ++jt) {
        f32x4 x = *(const f32x4*)(fb + 1 * 65536 + 16 * jt);
        efi[jt][0] = __expf(x[0]) * C_SCALE; efi[jt][1] = __expf(x[1]) * C_SCALE;
        efi[jt][2] = __expf(x[2]) * C_SCALE; efi[jt][3] = __expf(x[3]) * C_SCALE;
        r1v[jt] = *(const f32x4*)(fb + 2 * 65536 + 16 * jt);
        r2v[jt] = *(const f32x4*)(fb + 3 * 65536 + 16 * jt);
    }
    float logc_cur = LOG_C;            // log of scale baked into current efi

    f32x4 acc[8];                      // u[b][j], j = 16jt + 4q + r
    #pragma unroll
    for (int jt = 0; jt < 8; ++jt) acc[jt] = (f32x4){1.f, 1.f, 1.f, 1.f};
    float M     = (b == 0) ? 0.0f : NEG_VAL;  // init_fv zeroes only batch-0 row
    float alpha = 0.0f;

    #pragma unroll 8
    for (int t = 1; t < 128; ++t) {
        const bool upd = (t & 7) != 0;
        float sc_next = C_SCALE;       // scale for t+1's efi (boundary overrides)
        float lg_next = LOG_C;

        if (upd) {
            // ---- publish h = u * efi (scale inside efi; M bookkeeping) ----
            M += logc_cur;
            __builtin_amdgcn_wave_barrier();   // don't sink reads above writes
            #pragma unroll
            for (int jt = 0; jt < 8; ++jt) {
                f16x4 hh;
                hh[0] = (_Float16)(acc[jt][0] * efi[jt][0]);
                hh[1] = (_Float16)(acc[jt][1] * efi[jt][1]);
                hh[2] = (_Float16)(acc[jt][2] * efi[jt][2]);
                hh[3] = (_Float16)(acc[jt][3] * efi[jt][3]);
                *(f16x4*)(Hbuf + waddr[jt]) = hh;
            }
            __builtin_amdgcn_wave_barrier();   // same-wave DS pipe is in-order:
                                               // no s_barrier / lgkmcnt drain
            f16x8 B0 = *(const f16x8*)(Hbuf + raddr[0]);
            f16x8 B1 = *(const f16x8*)(Hbuf + raddr[1]);
            f16x8 B2 = *(const f16x8*)(Hbuf + raddr[2]);
            f16x8 B3 = *(const f16x8*)(Hbuf + raddr[3]);

            // ---- 32 MFMAs: 8 independent j-tiles, R9's exact 2-chain order
            f32x4 z = {0.f, 0.f, 0.f, 0.f};
            #pragma unroll
            for (int jt = 0; jt < 8; ++jt) {
                f32x4 da = __builtin_amdgcn_mfma_f32_16x16x32_f16(Afrag[jt][0], B0, z, 0, 0, 0);
                f32x4 db = __builtin_amdgcn_mfma_f32_16x16x32_f16(Afrag[jt][1], B1, z, 0, 0, 0);
                da = __builtin_amdgcn_mfma_f32_16x16x32_f16(Afrag[jt][2], B2, da, 0, 0, 0);
                db = __builtin_amdgcn_mfma_f32_16x16x32_f16(Afrag[jt][3], B3, db, 0, 0, 0);
                acc[jt] = da + db;
            }
        } else {
            // ---- boundary: alpha partial (sum) + exact renorm (max), all
            //      128 j are within this wave -> shfl-only, no LDS/barrier
            float sp[8];
            float m = acc[0][0];
            #pragma unroll
            for (int jt = 0; jt < 8; ++jt) {
                sp[jt] = acc[jt][0] * te[jt][0] + acc[jt][1] * te[jt][1]
                       + acc[jt][2] * te[jt][2] + acc[jt][3] * te[jt][3];
                m = fmaxf(m, fmaxf(fmaxf(acc[jt][0], acc[jt][1]),
                                   fmaxf(acc[jt][2], acc[jt][3])));
            }
            float s = ((sp[0] + sp[1]) + (sp[2] + sp[3]))
                    + ((sp[4] + sp[5]) + (sp[6] + sp[7]));
            s += __shfl_xor(s, 16, 64);
            s += __shfl_xor(s, 32, 64);
            m = fmaxf(m, __shfl_xor(m, 16, 64));
            m = fmaxf(m, __shfl_xor(m, 32, 64));

            alpha += M + __logf(s);    // per-batch, replicated over q
            // exact renorm folded into the NEXT update's scale
            sc_next = C_SCALE * __builtin_amdgcn_rcpf(m);
            lg_next = LOG_C + __logf(m);
        }

        // ---- rotate feat pipeline; build efi for t+1 with chosen scale ----
        if (t + 1 < 128) {
            #pragma unroll
            for (int jt = 0; jt < 8; ++jt) {
                efi[jt][0] = __expf(r1v[jt][0]) * sc_next;
                efi[jt][1] = __expf(r1v[jt][1]) * sc_next;
                efi[jt][2] = __expf(r1v[jt][2]) * sc_next;
                efi[jt][3] = __expf(r1v[jt][3]) * sc_next;
                r1v[jt] = r2v[jt];
                if (t + 3 < 128)
                    r2v[jt] = *(const f32x4*)(fb + (size_t)(t + 3) * 65536 + 16 * jt);
            }
            logc_cur = lg_next;
        }
    }

    // ---- terminal accumulation (sum only) ----
    {
        float sp[8];
        #pragma unroll
        for (int jt = 0; jt < 8; ++jt)
            sp[jt] = acc[jt][0] * te[jt][0] + acc[jt][1] * te[jt][1]
                   + acc[jt][2] * te[jt][2] + acc[jt][3] * te[jt][3];
        float s = ((sp[0] + sp[1]) + (sp[2] + sp[3]))
                + ((sp[4] + sp[5]) + (sp[6] + sp[7]));
        s += __shfl_xor(s, 16, 64);
        s += __shfl_xor(s, 32, 64);
        alpha += M + __logf(s);
    }

    // alpha replicated across the 4 q-lanes of each bloc: 64-lane sum = 4x
    // the 16-batch sum for this wave.
    float v = alpha;
    #pragma unroll
    for (int off = 1; off < 64; off <<= 1)
        v += __shfl_xor(v, off, 64);
    if (lane == 0)
        atomicAdd(out, v * (1.0f / (4.0f * 512.0f * 16.0f)));
}

extern "C" void kernel_launch(void* const* d_in, const int* in_sizes, int n_in,
                              void* d_out, int out_size, void* d_ws, size_t ws_size,
                              hipStream_t stream) {
    const float* feats = (const float*)d_in[0];   // [128,512,128] f32
    const float* trans = (const float*)d_in[1];   // [128,128] f32
    float* out = (float*)d_out;                   // scalar f32

    hipMemsetAsync(out, 0, sizeof(float), stream);
    crf_fwd<<<32, 64, 0, stream>>>(feats, trans, out);
}

// Round 3
// 194.790 us; speedup vs baseline: 1.0300x; 1.0300x over previous
//
#include <hip/hip_runtime.h>

// Segmented CRF forward (OneCrfCCKSDecoder), exp-domain + MFMA, R11.
// T=128, B=512, E=128, EVENTLEN=8, NEG=-10000.
//
// R10 post-mortem: wave-private with LDS transpose = 147us (worse than R9's
// 88): one wave per SIMD has no latency hiding, so the per-step LDS
// round-trip (8 ds_write -> lgkmcnt -> 4 ds_read) plus 32 serial-issue MFMAs
// all sit on the critical path.
//
// R11: eliminate the transpose entirely via MFMA layout chaining.
// v_mfma_f32_16x16x16f16 layouts: B[k=4q+r][n=bloc] and D[m=4q+r][n=bloc]
// are THE SAME lane mapping. Put j on M, batch on N:
//   step t:   acc[jt] (j=16jt+4q+r, b=bloc)  [D layout]
//   step t+1: B-frag[kp] needs h[k=16kp+4q+r][b=bloc] = acc[kp]*efi[kp] cast
//             to f16 -- register-only, no LDS, no shuffles, no barriers.
// Update = build 8 B-frags (32 mul + 32 cvt) + 64 MFMAs (8 jt x 8 kp,
// 16 independent chains of depth 4). Zero LDS in the whole kernel.
// Grid = 32 blocks x 64 threads, fully wave-private.
//
// A[m=lane&15][k=4q+i] => Afrag[jt][kp][r] = exp(trans[16jt+bloc][16kp+4q+r]).
// Renorm identical to validated R9/R10: fixed e^-6 per-step scale in efi
// (M += 6 bookkeeping), exact per-batch max-renorm at event boundaries
// (pure shfl_xor reductions; all 128 j live in-wave).

typedef _Float16 f16x4 __attribute__((ext_vector_type(4)));
typedef float    f32x4 __attribute__((ext_vector_type(4)));

#define NEG_VAL   (-10000.0f)
#define C_SCALE   0.0024787521766663585f   // e^-6
#define LOG_C     6.0f

__global__ __launch_bounds__(64, 1)
void crf_fwd(const float* __restrict__ feats,   // [128][512][128] f32
             const float* __restrict__ trans,   // [128][128] f32
             float* __restrict__ out)
{
    const int lane = threadIdx.x & 63;
    const int bloc = lane & 15;        // batch-in-tile (n role everywhere)
    const int q    = lane >> 4;        // quad 0..3
    const int b    = blockIdx.x * 16 + bloc;   // global batch

    // ---- A fragments: Afrag[jt][kp][r] = exp(trans[16jt+bloc][16kp+4q+r])
    f16x4 Afrag[8][8];
    #pragma unroll
    for (int jt = 0; jt < 8; ++jt) {
        const float* rowp = trans + (size_t)(16 * jt + bloc) * 128;
        #pragma unroll
        for (int kp = 0; kp < 8; ++kp) {
            f32x4 x = *(const f32x4*)(rowp + 16 * kp + 4 * q);
            f16x4 f;
            f[0] = (_Float16)__expf(x[0]);
            f[1] = (_Float16)__expf(x[1]);
            f[2] = (_Float16)__expf(x[2]);
            f[3] = (_Float16)__expf(x[3]);
            Afrag[jt][kp] = f;
        }
    }
    // te[kp][r] = exp(trans[127][16kp+4q+r])  (acc-layout aligned)
    f32x4 te[8];
    #pragma unroll
    for (int kp = 0; kp < 8; ++kp) {
        f32x4 x = *(const f32x4*)(trans + 127 * 128 + 16 * kp + 4 * q);
        te[kp][0] = __expf(x[0]); te[kp][1] = __expf(x[1]);
        te[kp][2] = __expf(x[2]); te[kp][3] = __expf(x[3]);
    }

    // ---- feat pipeline: lane needs feat[t][b][16kp+4q+r], kp=0..7 ----
    const float* fb = feats + (size_t)b * 128 + 4 * q;
    f32x4 efi[8], r1v[8], r2v[8];
    #pragma unroll
    for (int kp = 0; kp < 8; ++kp) {
        f32x4 x = *(const f32x4*)(fb + 1 * 65536 + 16 * kp);
        efi[kp][0] = __expf(x[0]) * C_SCALE; efi[kp][1] = __expf(x[1]) * C_SCALE;
        efi[kp][2] = __expf(x[2]) * C_SCALE; efi[kp][3] = __expf(x[3]) * C_SCALE;
        r1v[kp] = *(const f32x4*)(fb + 2 * 65536 + 16 * kp);
        r2v[kp] = *(const f32x4*)(fb + 3 * 65536 + 16 * kp);
    }
    float logc_cur = LOG_C;            // log of scale baked into current efi

    f32x4 acc[8];                      // u[b=bloc][j=16i+4q+r], D/B layout
    #pragma unroll
    for (int i = 0; i < 8; ++i) acc[i] = (f32x4){1.f, 1.f, 1.f, 1.f};
    float M     = (b == 0) ? 0.0f : NEG_VAL;  // init_fv zeroes only batch-0 row
    float alpha = 0.0f;

    #pragma unroll 8
    for (int t = 1; t < 128; ++t) {
        const bool upd = (t & 7) != 0;
        float sc_next = C_SCALE;       // scale for t+1's efi (boundary overrides)
        float lg_next = LOG_C;

        if (upd) {
            // ---- B-frags: h[k][b] = acc[kp]*efi[kp] -> f16, register-only
            M += logc_cur;
            f16x4 Bf[8];
            #pragma unroll
            for (int kp = 0; kp < 8; ++kp) {
                Bf[kp][0] = (_Float16)(acc[kp][0] * efi[kp][0]);
                Bf[kp][1] = (_Float16)(acc[kp][1] * efi[kp][1]);
                Bf[kp][2] = (_Float16)(acc[kp][2] * efi[kp][2]);
                Bf[kp][3] = (_Float16)(acc[kp][3] * efi[kp][3]);
            }
            // ---- 64 MFMAs: 8 jt x 8 kp; 2 chains of depth 4 per jt ----
            f32x4 z = {0.f, 0.f, 0.f, 0.f};
            #pragma unroll
            for (int jt = 0; jt < 8; ++jt) {
                f32x4 da = __builtin_amdgcn_mfma_f32_16x16x16f16(Afrag[jt][0], Bf[0], z, 0, 0, 0);
                f32x4 db = __builtin_amdgcn_mfma_f32_16x16x16f16(Afrag[jt][1], Bf[1], z, 0, 0, 0);
                da = __builtin_amdgcn_mfma_f32_16x16x16f16(Afrag[jt][2], Bf[2], da, 0, 0, 0);
                db = __builtin_amdgcn_mfma_f32_16x16x16f16(Afrag[jt][3], Bf[3], db, 0, 0, 0);
                da = __builtin_amdgcn_mfma_f32_16x16x16f16(Afrag[jt][4], Bf[4], da, 0, 0, 0);
                db = __builtin_amdgcn_mfma_f32_16x16x16f16(Afrag[jt][5], Bf[5], db, 0, 0, 0);
                da = __builtin_amdgcn_mfma_f32_16x16x16f16(Afrag[jt][6], Bf[6], da, 0, 0, 0);
                db = __builtin_amdgcn_mfma_f32_16x16x16f16(Afrag[jt][7], Bf[7], db, 0, 0, 0);
                acc[jt] = da + db;     // Bf snapshot taken; safe to overwrite
            }
        } else {
            // ---- boundary: alpha partial (sum) + exact renorm (max);
            //      all 128 j in-wave -> shfl-only, no LDS/barrier
            float sp[8];
            float m = acc[0][0];
            #pragma unroll
            for (int kp = 0; kp < 8; ++kp) {
                sp[kp] = acc[kp][0] * te[kp][0] + acc[kp][1] * te[kp][1]
                       + acc[kp][2] * te[kp][2] + acc[kp][3] * te[kp][3];
                m = fmaxf(m, fmaxf(fmaxf(acc[kp][0], acc[kp][1]),
                                   fmaxf(acc[kp][2], acc[kp][3])));
            }
            float s = ((sp[0] + sp[1]) + (sp[2] + sp[3]))
                    + ((sp[4] + sp[5]) + (sp[6] + sp[7]));
            s += __shfl_xor(s, 16, 64);
            s += __shfl_xor(s, 32, 64);
            m = fmaxf(m, __shfl_xor(m, 16, 64));
            m = fmaxf(m, __shfl_xor(m, 32, 64));

            alpha += M + __logf(s);    // per-batch, replicated over q
            // exact renorm folded into the NEXT update's scale
            sc_next = C_SCALE * __builtin_amdgcn_rcpf(m);
            lg_next = LOG_C + __logf(m);
        }

        // ---- rotate feat pipeline; build efi for t+1 with chosen scale ----
        if (t + 1 < 128) {
            #pragma unroll
            for (int kp = 0; kp < 8; ++kp) {
                efi[kp][0] = __expf(r1v[kp][0]) * sc_next;
                efi[kp][1] = __expf(r1v[kp][1]) * sc_next;
                efi[kp][2] = __expf(r1v[kp][2]) * sc_next;
                efi[kp][3] = __expf(r1v[kp][3]) * sc_next;
                r1v[kp] = r2v[kp];
                if (t + 3 < 128)
                    r2v[kp] = *(const f32x4*)(fb + (size_t)(t + 3) * 65536 + 16 * kp);
            }
            logc_cur = lg_next;
        }
    }

    // ---- terminal accumulation (sum only) ----
    {
        float sp[8];
        #pragma unroll
        for (int kp = 0; kp < 8; ++kp)
            sp[kp] = acc[kp][0] * te[kp][0] + acc[kp][1] * te[kp][1]
                   + acc[kp][2] * te[kp][2] + acc[kp][3] * te[kp][3];
        float s = ((sp[0] + sp[1]) + (sp[2] + sp[3]))
                + ((sp[4] + sp[5]) + (sp[6] + sp[7]));
        s += __shfl_xor(s, 16, 64);
        s += __shfl_xor(s, 32, 64);
        alpha += M + __logf(s);
    }

    // alpha replicated across the 4 q-lanes of each bloc: 64-lane sum = 4x
    // the 16-batch sum for this wave.
    float v = alpha;
    #pragma unroll
    for (int off = 1; off < 64; off <<= 1)
        v += __shfl_xor(v, off, 64);
    if (lane == 0)
        atomicAdd(out, v * (1.0f / (4.0f * 512.0f * 16.0f)));
}

extern "C" void kernel_launch(void* const* d_in, const int* in_sizes, int n_in,
                              void* d_out, int out_size, void* d_ws, size_t ws_size,
                              hipStream_t stream) {
    const float* feats = (const float*)d_in[0];   // [128,512,128] f32
    const float* trans = (const float*)d_in[1];   // [128,128] f32
    float* out = (float*)d_out;                   // scalar f32

    hipMemsetAsync(out, 0, sizeof(float), stream);
    crf_fwd<<<32, 64, 0, stream>>>(feats, trans, out);
}